// Round 2
// baseline (849.787 us; speedup 1.0000x reference)
//
#include <hip/hip_runtime.h>
#include <cmath>

// Problem constants (fixed by the reference; active_size input == 512)
#define NB   32768
#define DIN  128
#define DMAX 1024
#define A    512

// ws layout (floats):
//   [0, 65536)              WinT [128 k][512 n]  = W_in[n][k]
//   [65536 + g*65536, ...)  WgT_g[128 k][512 n]  = W_gate[g*512+n][k],  g=0,1,2
// total 4*65536 floats = 1 MB

__global__ __launch_bounds__(256) void transpose_w(
    const float* __restrict__ Win, const float* __restrict__ Wg,
    float* __restrict__ ws)
{
    int idx = blockIdx.x * 256 + threadIdx.x;   // 262144 total
    int m = idx >> 16;                           // 0 = Win, 1..3 = gate g = m-1
    int r = idx & 65535;
    int k = r >> 9;                              // 0..127
    int n = r & 511;                             // 0..511
    float v = (m == 0) ? Win[n * DIN + k]
                       : Wg[(((m - 1) << 9) + n) * DIN + k];
    ws[idx] = v;
}

__device__ __forceinline__ float sigm(float x) { return 1.0f / (1.0f + expf(-x)); }

// Wave-level microkernel: each wave computes 64 batch rows (lane = row) x 32 cols.
// A staged in LDS (m-major, 1 ds_read_b128 per 4 k per lane).
// B read directly from global with wave-uniform addresses -> scalar loads,
// feeding v_fmac_f32's SGPR operand. No LDS for B at all.
__global__ __launch_bounds__(256, 4) void gser_main(
    const float* __restrict__ X,    // [NB, DIN]
    const float* __restrict__ P,    // [NB, DMAX]
    const float* __restrict__ Wres, // [DMAX, DMAX], use [k<512][j<512]
    const float* __restrict__ wsW,  // WinT + WgT (see layout above)
    const float* __restrict__ lrp,  // [DMAX]
    const float* __restrict__ stp,  // [DMAX]
    float* __restrict__ out)        // [NB, DMAX]
{
    __shared__ float As[64][68];    // 64 rows x 64 k, stride 68 (17 float4: bank-balanced)

    const int t    = threadIdx.x;
    const int lane = t & 63;
    const int wid  = __builtin_amdgcn_readfirstlane(t >> 6);  // force SGPR
    const int m0   = blockIdx.y * 64;
    const int j0   = blockIdx.x * 128;
    const int jw   = j0 + wid * 32;   // this wave's 32-col window (SGPR)

    float acc[32];
#pragma unroll
    for (int i = 0; i < 32; ++i) acc[i] = 0.f;

    // ---- stage one 64x64 A-chunk into LDS ----
    auto stage = [&](const float* Asrc, int lda) {
        __syncthreads();
        const int row = t >> 2;       // 0..63
        const int c0  = t & 3;
        const float4* g = reinterpret_cast<const float4*>(Asrc + (size_t)row * lda);
#pragma unroll
        for (int q = 0; q < 4; ++q) {
            float4 v = g[c0 + q * 4];
            *reinterpret_cast<float4*>(&As[row][(c0 + q * 4) * 4]) = v;
        }
        __syncthreads();
    };

    // ---- accumulate 64 k-steps: acc[n] += A[lane][k] * B[k][jw+n] ----
    auto accum = [&](const float* Bsrc, int ldb, float* ac) {
        for (int k4 = 0; k4 < 16; ++k4) {
            float4 a4 = *reinterpret_cast<const float4*>(&As[lane][k4 * 4]);
#pragma unroll
            for (int u = 0; u < 4; ++u) {
                const float a = (&a4.x)[u];
                const float* br = Bsrc + (size_t)(k4 * 4 + u) * ldb + jw;  // wave-uniform
#pragma unroll
                for (int j4 = 0; j4 < 8; ++j4) {
                    float4 b = *reinterpret_cast<const float4*>(br + j4 * 4);
                    ac[j4 * 4 + 0] = fmaf(a, b.x, ac[j4 * 4 + 0]);
                    ac[j4 * 4 + 1] = fmaf(a, b.y, ac[j4 * 4 + 1]);
                    ac[j4 * 4 + 2] = fmaf(a, b.z, ac[j4 * 4 + 2]);
                    ac[j4 * 4 + 3] = fmaf(a, b.w, ac[j4 * 4 + 3]);
                }
            }
        }
    };

    // ---- main: reservoir part, K = 512 (A from P, B from Wres[k][j]) ----
    for (int c = 0; c < 8; ++c) {
        stage(P + (size_t)m0 * DMAX + c * 64, DMAX);
        accum(Wres + (size_t)(c * 64) * DMAX, DMAX, acc);
    }
    // ---- main: input part, K = 128 (A from X, B from WinT) ----
    for (int c = 0; c < 2; ++c) {
        stage(X + (size_t)m0 * DIN + c * 64, DIN);
        accum(wsW + (size_t)(c * 64) * 512, 512, acc);
    }
    // acc now holds s1 = input_part + reservoir_part

    float accg[32];

    // ---- i gate: acc = tanh(sigmoid(accg) * acc) ----
#pragma unroll
    for (int i = 0; i < 32; ++i) accg[i] = 0.f;
    for (int c = 0; c < 2; ++c) {
        stage(X + (size_t)m0 * DIN + c * 64, DIN);
        accum(wsW + 65536 + 0 * 65536 + (size_t)(c * 64) * 512, 512, accg);
    }
#pragma unroll
    for (int i = 0; i < 32; ++i) acc[i] = tanhf(sigm(accg[i]) * acc[i]);

    // ---- f gate: acc = (1-leak)*fg*prev + leak*acc ----
#pragma unroll
    for (int i = 0; i < 32; ++i) accg[i] = 0.f;
    for (int c = 0; c < 2; ++c) {
        stage(X + (size_t)m0 * DIN + c * 64, DIN);
        accum(wsW + 65536 + 1 * 65536 + (size_t)(c * 64) * 512, 512, accg);
    }
    {
        const float* prow = P + (size_t)(m0 + lane) * DMAX + jw;
#pragma unroll
        for (int j4 = 0; j4 < 8; ++j4) {
            float4 pv = *reinterpret_cast<const float4*>(prow + j4 * 4);
#pragma unroll
            for (int c = 0; c < 4; ++c) {
                const int i = j4 * 4 + c;
                const float lk = sigm(lrp[jw + i]);           // uniform -> scalar load
                const float fg = sigm(accg[i]);
                acc[i] = (1.0f - lk) * (fg * (&pv.x)[c]) + lk * acc[i];
            }
        }
    }

    // ---- o gate: st = sigmoid(accg)*acc; spike threshold; store ----
#pragma unroll
    for (int i = 0; i < 32; ++i) accg[i] = 0.f;
    for (int c = 0; c < 2; ++c) {
        stage(X + (size_t)m0 * DIN + c * 64, DIN);
        accum(wsW + 65536 + 2 * 65536 + (size_t)(c * 64) * 512, 512, accg);
    }
    {
        const size_t orow = (size_t)(m0 + lane) * DMAX;
#pragma unroll
        for (int j4 = 0; j4 < 8; ++j4) {
            float4 res;
#pragma unroll
            for (int c = 0; c < 4; ++c) {
                const int i = j4 * 4 + c;
                const float thr = log1pf(expf(stp[jw + i]));  // softplus, uniform
                float st = sigm(accg[i]) * acc[i];
                st = (st > thr) ? (st - thr) : st;
                (&res.x)[c] = st;
            }
            *reinterpret_cast<float4*>(out + orow + jw + j4 * 4) = res;
        }
        // zero-pad cols [512, 1024): this wave covers 512+jw .. 512+jw+31
        float4 z; z.x = 0.f; z.y = 0.f; z.z = 0.f; z.w = 0.f;
#pragma unroll
        for (int j4 = 0; j4 < 8; ++j4)
            *reinterpret_cast<float4*>(out + orow + A + jw + j4 * 4) = z;
    }
}

extern "C" void kernel_launch(void* const* d_in, const int* in_sizes, int n_in,
                              void* d_out, int out_size, void* d_ws, size_t ws_size,
                              hipStream_t stream) {
    const float* X    = (const float*)d_in[0];
    const float* P    = (const float*)d_in[1];
    const float* Wres = (const float*)d_in[2];
    const float* Win  = (const float*)d_in[3];
    const float* Wg   = (const float*)d_in[4];
    const float* lrp  = (const float*)d_in[5];
    const float* stp  = (const float*)d_in[6];
    float* out = (float*)d_out;
    float* ws  = (float*)d_ws;

    // 1) transpose W_in / W_gate into ws (k-major panels for scalar B loads)
    hipLaunchKernelGGL(transpose_w, dim3(1024), dim3(256), 0, stream, Win, Wg, ws);
    // 2) fused GEMM + gating
    hipLaunchKernelGGL(gser_main, dim3(4, 512), dim3(256), 0, stream,
                       X, P, Wres, ws, lrp, stp, out);
}